// Round 3
// baseline (415.850 us; speedup 1.0000x reference)
//
#include <hip/hip_runtime.h>
#include <math.h>

#define NBIN 4096
#define CAPC 4096
#define KSEL 128
#define HDIM 212
#define DAC  16
#define EPSF 1e-8f
#define GRID1 2048

// meta: [0]=candidate count, [1]=keyHi, [4]=done ctr pass1, [5]=done ctr pass2
__global__ void k_init(const float* __restrict__ x, float* __restrict__ xn,
                       unsigned* __restrict__ hist, unsigned* __restrict__ meta) {
    int t = threadIdx.x;
    __shared__ float rs;
    if (t < 32) {
        float v = x[t];
        float s = v * v;
        #pragma unroll
        for (int o = 16; o >= 1; o >>= 1) s += __shfl_down(s, o);
        if (t == 0) rs = rsqrtf(s + EPSF);
    }
    __syncthreads();
    if (t < 32) xn[t] = x[t] * rs;
    for (int b = t; b < NBIN; b += blockDim.x) hist[b] = 0u;
    if (t < 8) meta[t] = 0u;
}

// Grid-stride, 2048 blocks. 8 threads per row, one float4 each.
// Last-finishing block scans the histogram and writes the key threshold.
__global__ __launch_bounds__(256) void k_cos_hist(
        const float4* __restrict__ obs4, const float* __restrict__ xn,
        float* __restrict__ cosb, unsigned* __restrict__ hist,
        unsigned* __restrict__ meta, long total) {
    __shared__ unsigned lhist[NBIN];
    __shared__ float xns[32];
    __shared__ unsigned psum[256];
    __shared__ unsigned isLast;
    for (int b = threadIdx.x; b < NBIN; b += blockDim.x) lhist[b] = 0u;
    if (threadIdx.x < 32) xns[threadIdx.x] = xn[threadIdx.x];
    __syncthreads();

    const long stride = (long)gridDim.x * blockDim.x;
    long g0 = (long)blockIdx.x * blockDim.x + threadIdx.x;
    const int r = (int)(g0 & 7);   // stride % 8 == 0 -> constant per thread
    const float c0 = xns[4*r+0], c1 = xns[4*r+1], c2 = xns[4*r+2], c3 = xns[4*r+3];

    #define PROC(G) do {                                                        \
        float4 v = obs4[(G)];                                                   \
        float dot = v.x * c0 + v.y * c1 + v.z * c2 + v.w * c3;                  \
        float nrm = v.x*v.x + v.y*v.y + v.z*v.z + v.w*v.w;                      \
        _Pragma("unroll")                                                       \
        for (int o = 1; o < 8; o <<= 1) {                                       \
            dot += __shfl_xor(dot, o);                                          \
            nrm += __shfl_xor(nrm, o);                                          \
        }                                                                       \
        if (r == 0) {                                                           \
            long row = (G) >> 3;                                                \
            float cd = 1.0f - dot * rsqrtf(nrm + EPSF);                         \
            cosb[row] = cd;                                                     \
            unsigned u = __float_as_uint(cd);                                   \
            unsigned key = (u & 0x80000000u) ? ~u : (u | 0x80000000u);          \
            atomicAdd(&lhist[key >> 20], 1u);                                   \
        }                                                                       \
    } while (0)

    long g = g0;
    for (; g + 3*stride < total; g += 4*stride) {
        PROC(g);
        PROC(g + stride);
        PROC(g + 2*stride);
        PROC(g + 3*stride);
    }
    for (; g < total; g += stride) PROC(g);
    #undef PROC

    __syncthreads();
    for (int b = threadIdx.x; b < NBIN; b += blockDim.x) {
        unsigned c = lhist[b];
        if (c) atomicAdd(&hist[b], c);
    }

    // ---- tail: last block to finish computes the K-th-element threshold ----
    __threadfence();
    if (threadIdx.x == 0) {
        unsigned prev = atomicAdd(&meta[4], 1u);
        isLast = (prev == gridDim.x - 1u) ? 1u : 0u;
    }
    __syncthreads();
    if (!isLast) return;
    __threadfence();   // acquire all blocks' hist flushes

    int t = threadIdx.x;
    unsigned c[16];
    unsigned local = 0;
    #pragma unroll
    for (int q = 0; q < 16; q++) { c[q] = hist[16*t + q]; local += c[q]; }
    psum[t] = local;
    __syncthreads();
    for (int o = 1; o < 256; o <<= 1) {
        unsigned v = (t >= o) ? psum[t - o] : 0u;
        __syncthreads();
        psum[t] += v;
        __syncthreads();
    }
    unsigned incl = psum[t];
    unsigned excl = incl - local;
    if (excl < KSEL && KSEL <= incl) {
        unsigned cum = excl;
        int B = 16*t;
        for (int q = 0; q < 16; q++) {
            cum += c[q];
            if (cum >= KSEL) { B = 16*t + q; break; }
        }
        meta[1] = (B >= NBIN - 1) ? 0xFFFFFFFFu : ((unsigned)(B + 1) << 20);
    }
}

// Compact candidates below threshold; last-finishing block runs the exact
// 128-selection (radix-select over (key,idx)) + MLP + softmax + output.
__global__ __launch_bounds__(512) void k_compact_final(
        const float4* __restrict__ cos4, unsigned* __restrict__ meta,
        float* __restrict__ cval, int* __restrict__ cidx, int n4, int N,
        const float* __restrict__ acs,
        const float* __restrict__ w_in, const float* __restrict__ b_in,
        const float* __restrict__ w2, const float* __restrict__ b2,
        const float* __restrict__ w3, const float* __restrict__ b3,
        const float* __restrict__ w_out, const float* __restrict__ b_out,
        float* __restrict__ out) {
    __shared__ unsigned kv[CAPC];
    __shared__ int      idv[CAPC];
    __shared__ unsigned char act[CAPC];
    __shared__ unsigned hist2[256];
    __shared__ unsigned remArr[9];
    __shared__ unsigned pivB[8];
    __shared__ unsigned selB_sh;
    __shared__ unsigned scnt;
    __shared__ unsigned skey[KSEL];
    __shared__ int      sidx[KSEL];
    __shared__ float    sval[KSEL];
    __shared__ float d[KSEL];
    __shared__ int   id2[KSEL];
    __shared__ float h1[HDIM], h2[HDIM], h3[HDIM], lg[KSEL];
    __shared__ float smax_sh, rsum_sh;
    __shared__ unsigned isLast;

    unsigned keyHi = meta[1];
    int g = blockIdx.x * blockDim.x + threadIdx.x;
    if (g < n4) {
        float4 v = cos4[g];
        float vv[4] = {v.x, v.y, v.z, v.w};
        #pragma unroll
        for (int q = 0; q < 4; q++) {
            int i = g*4 + q;
            if (i < N) {
                unsigned u = __float_as_uint(vv[q]);
                unsigned key = (u & 0x80000000u) ? ~u : (u | 0x80000000u);
                if (key < keyHi) {
                    unsigned pos = atomicAdd(&meta[0], 1u);
                    if (pos < CAPC) { cval[pos] = vv[q]; cidx[pos] = i; }
                }
            }
        }
    }

    __threadfence();
    if (threadIdx.x == 0) {
        unsigned prev = atomicAdd(&meta[5], 1u);
        isLast = (prev == gridDim.x - 1u) ? 1u : 0u;
    }
    __syncthreads();
    if (!isLast) return;
    __threadfence();   // acquire all blocks' cval/cidx/meta[0] writes

    const int t = threadIdx.x;
    int M = (int)meta[0];
    if (M > CAPC) M = CAPC;

    for (int i = t; i < M; i += 512) {
        float v = cval[i];
        unsigned u = __float_as_uint(v);
        kv[i]  = (u & 0x80000000u) ? ~u : (u | 0x80000000u);
        idv[i] = cidx[i];
        act[i] = 1;
    }
    if (t == 0) remArr[0] = KSEL - 1;   // 0-indexed rank of the pivot
    if (t < KSEL) {                     // safety init
        skey[t] = 0xFFFFFFFFu; sidx[t] = 0x7FFFFFFF; sval[t] = 0.f;
        d[t] = 0.f; id2[t] = 0;
    }
    __syncthreads();

    // 8-round MSB radix select over the 64-bit key (key32, idx32)
    for (int r = 0; r < 8; r++) {
        if (t < 256) hist2[t] = 0u;
        __syncthreads();
        for (int i = t; i < M; i += 512) {
            if (act[i]) {
                unsigned b = (r < 4) ? ((kv[i] >> ((3-r)*8)) & 0xFFu)
                                     : (((unsigned)idv[i] >> ((7-r)*8)) & 0xFFu);
                atomicAdd(&hist2[b], 1u);
            }
        }
        __syncthreads();
        if (t < 64) {
            unsigned s0 = hist2[4*t], s1 = hist2[4*t+1],
                     s2 = hist2[4*t+2], s3 = hist2[4*t+3];
            unsigned tot = s0 + s1 + s2 + s3;
            unsigned sc = tot;
            #pragma unroll
            for (int o = 1; o < 64; o <<= 1) {
                unsigned v2 = __shfl_up(sc, o);
                if (t >= o) sc += v2;
            }
            unsigned cb = sc - tot;          // exclusive prefix of this lane's 4 bins
            unsigned rm = remArr[r];
            unsigned ss[4] = {s0, s1, s2, s3};
            #pragma unroll
            for (int q = 0; q < 4; q++) {
                if (cb <= rm && rm < cb + ss[q]) {
                    selB_sh = 4*t + q;
                    pivB[r] = 4*t + q;
                    remArr[r+1] = rm - cb;
                }
                cb += ss[q];
            }
        }
        __syncthreads();
        unsigned sb = selB_sh;
        for (int i = t; i < M; i += 512) {
            if (act[i]) {
                unsigned b = (r < 4) ? ((kv[i] >> ((3-r)*8)) & 0xFFu)
                                     : (((unsigned)idv[i] >> ((7-r)*8)) & 0xFFu);
                if (b != sb) act[i] = 0;
            }
        }
        __syncthreads();
    }

    unsigned kvP = (pivB[0]<<24) | (pivB[1]<<16) | (pivB[2]<<8) | pivB[3];
    unsigned idP = (pivB[4]<<24) | (pivB[5]<<16) | (pivB[6]<<8) | pivB[7];
    if (t == 0) scnt = 0u;
    __syncthreads();

    // exactly-128 selection: (key, idx) <= pivot
    for (int i = t; i < M; i += 512) {
        unsigned k = kv[i];
        unsigned ui = (unsigned)idv[i];
        if (k < kvP || (k == kvP && ui <= idP)) {
            unsigned p = atomicAdd(&scnt, 1u);
            if (p < KSEL) {
                skey[p] = k;
                sidx[p] = idv[i];
                unsigned u = (k & 0x80000000u) ? (k & 0x7FFFFFFFu) : ~k;
                sval[p] = __uint_as_float(u);
            }
        }
    }
    __syncthreads();

    // pairwise rank -> sorted ascending by (val, idx), matching lax.top_k
    if (t < KSEL) {
        unsigned mk = skey[t], mi = (unsigned)sidx[t];
        int rank = 0;
        for (int j = 0; j < KSEL; j++) {
            unsigned jk = skey[j], ji = (unsigned)sidx[j];
            rank += (jk < mk || (jk == mk && ji < mi)) ? 1 : 0;
        }
        d[rank] = sval[t];
        id2[rank] = sidx[t];
    }
    __syncthreads();

    // MLP: [128] -> [212] -> [212] -> [212] -> [128]
    if (t < HDIM) {
        float s = b_in[t];
        const float* wr = &w_in[t * KSEL];
        for (int j = 0; j < KSEL; j++) s += wr[j] * d[j];
        h1[t] = s > 0.f ? s : 0.f;
    }
    __syncthreads();
    if (t < HDIM) {
        float s = b2[t];
        const float* wr = &w2[t * HDIM];
        for (int j = 0; j < HDIM; j++) s += wr[j] * h1[j];
        h2[t] = s > 0.f ? s : 0.f;
    }
    __syncthreads();
    if (t < HDIM) {
        float s = b3[t];
        const float* wr = &w3[t * HDIM];
        for (int j = 0; j < HDIM; j++) s += wr[j] * h2[j];
        h3[t] = s > 0.f ? s : 0.f;
    }
    __syncthreads();
    if (t < KSEL) {
        float s = b_out[t];
        const float* wr = &w_out[t * HDIM];
        for (int j = 0; j < HDIM; j++) s += wr[j] * h3[j];
        lg[t] = s;
    }
    __syncthreads();

    // parallel softmax over 128 logits
    if (t < 64) {
        float a = fmaxf(lg[t], lg[t + 64]);
        #pragma unroll
        for (int o = 32; o >= 1; o >>= 1) a = fmaxf(a, __shfl_xor(a, o));
        if (t == 0) smax_sh = a;
    }
    __syncthreads();
    if (t < KSEL) lg[t] = __expf(lg[t] - smax_sh);
    __syncthreads();
    if (t < 64) {
        float s = lg[t] + lg[t + 64];
        #pragma unroll
        for (int o = 32; o >= 1; o >>= 1) s += __shfl_xor(s, o);
        if (t == 0) rsum_sh = 1.0f / s;
    }
    __syncthreads();

    // weighted action sum -> out[16]
    if (t < DAC) {
        float s = 0.f;
        for (int j = 0; j < KSEL; j++)
            s += lg[j] * acs[(size_t)id2[j] * DAC + t];
        out[t] = s * rsum_sh;
    }
}

extern "C" void kernel_launch(void* const* d_in, const int* in_sizes, int n_in,
                              void* d_out, int out_size, void* d_ws, size_t ws_size,
                              hipStream_t stream) {
    const float* obs   = (const float*)d_in[0];
    const float* acs   = (const float*)d_in[1];
    const float* x     = (const float*)d_in[2];
    const float* w_in  = (const float*)d_in[3];
    const float* b_in  = (const float*)d_in[4];
    const float* w2    = (const float*)d_in[5];
    const float* b2    = (const float*)d_in[6];
    const float* w3    = (const float*)d_in[7];
    const float* b3    = (const float*)d_in[8];
    const float* w_out = (const float*)d_in[9];
    const float* b_out = (const float*)d_in[10];
    float* out = (float*)d_out;

    int N = in_sizes[0] / 32;

    char* ws = (char*)d_ws;
    float*    xn   = (float*)ws;                       // 32 floats
    float*    cosb = (float*)(ws + 256);               // N floats
    size_t histOff = 256 + (((size_t)N * 4 + 255) / 256) * 256;
    unsigned* hist = (unsigned*)(ws + histOff);        // 4096 u32
    unsigned* meta = (unsigned*)(ws + histOff + NBIN * 4);  // 8 u32
    float*    cval = (float*)(ws + histOff + NBIN * 4 + 256);
    int*      cidx = (int*)(ws + histOff + NBIN * 4 + 256 + CAPC * 4);

    k_init<<<1, 256, 0, stream>>>(x, xn, hist, meta);

    long total = (long)N * 8;                          // float4s in obs
    k_cos_hist<<<GRID1, 256, 0, stream>>>((const float4*)obs, xn, cosb, hist,
                                          meta, total);

    int n4 = (N + 3) / 4;
    int g2 = (n4 + 511) / 512;
    k_compact_final<<<g2, 512, 0, stream>>>((const float4*)cosb, meta,
                                            cval, cidx, n4, N, acs,
                                            w_in, b_in, w2, b2, w3, b3,
                                            w_out, b_out, out);
}

// Round 4
// 132.909 us; speedup vs baseline: 3.1288x; 3.1288x over previous
//
#include <hip/hip_runtime.h>
#include <math.h>

#define NBIN 4096
#define CAPC 4096
#define KSEL 128
#define HDIM 212
#define DAC  16
#define EPSF 1e-8f
#define GRID1 2048

// meta: [0]=candidate count, [1]=keyHi threshold
__global__ void k_init(const float* __restrict__ x, float* __restrict__ xn,
                       unsigned* __restrict__ hist, unsigned* __restrict__ meta) {
    int t = threadIdx.x;
    __shared__ float rs;
    if (t < 32) {
        float v = x[t];
        float s = v * v;
        #pragma unroll
        for (int o = 16; o >= 1; o >>= 1) s += __shfl_down(s, o);
        if (t == 0) rs = rsqrtf(s + EPSF);
    }
    __syncthreads();
    if (t < 32) xn[t] = x[t] * rs;
    for (int b = t; b < NBIN; b += blockDim.x) hist[b] = 0u;
    if (t < 8) meta[t] = 0u;
}

// Thread-per-row: one obs row = 32 floats = 128B = one cache line.
// 8 independent float4 loads per row, zero cross-lane ops.
__global__ __launch_bounds__(256) void k_cos_hist(
        const float4* __restrict__ obs4, const float* __restrict__ xn,
        float* __restrict__ cosb, unsigned* __restrict__ hist, int N) {
    __shared__ unsigned lhist[NBIN];
    __shared__ float xs[32];
    for (int b = threadIdx.x; b < NBIN; b += 256) lhist[b] = 0u;
    if (threadIdx.x < 32) xs[threadIdx.x] = xn[threadIdx.x];
    __syncthreads();

    float4 X[8];
    #pragma unroll
    for (int q = 0; q < 8; q++)
        X[q] = make_float4(xs[4*q+0], xs[4*q+1], xs[4*q+2], xs[4*q+3]);

    const int stride = gridDim.x * blockDim.x;
    for (int row = blockIdx.x * blockDim.x + threadIdx.x; row < N; row += stride) {
        const float4* rp = obs4 + (size_t)row * 8;
        float4 v0 = rp[0], v1 = rp[1], v2 = rp[2], v3 = rp[3];
        float4 v4 = rp[4], v5 = rp[5], v6 = rp[6], v7 = rp[7];

        #define D4(v, q) ((v).x*X[q].x + (v).y*X[q].y + (v).z*X[q].z + (v).w*X[q].w)
        #define N4(v)    ((v).x*(v).x + (v).y*(v).y + (v).z*(v).z + (v).w*(v).w)
        float dA = D4(v0,0) + D4(v1,1);
        float dB = D4(v2,2) + D4(v3,3);
        float dC = D4(v4,4) + D4(v5,5);
        float dD = D4(v6,6) + D4(v7,7);
        float nA = N4(v0) + N4(v1);
        float nB = N4(v2) + N4(v3);
        float nC = N4(v4) + N4(v5);
        float nD = N4(v6) + N4(v7);
        #undef D4
        #undef N4
        float dot = (dA + dB) + (dC + dD);
        float nrm = (nA + nB) + (nC + nD);

        float cd = 1.0f - dot * rsqrtf(nrm + EPSF);
        cosb[row] = cd;
        unsigned u = __float_as_uint(cd);
        unsigned key = (u & 0x80000000u) ? ~u : (u | 0x80000000u);
        atomicAdd(&lhist[key >> 20], 1u);
    }

    __syncthreads();
    for (int b = threadIdx.x; b < NBIN; b += 256) {
        unsigned c = lhist[b];
        if (c) atomicAdd(&hist[b], c);
    }
}

// Single tiny block: prefix-scan histogram, find bin holding the K-th element.
__global__ __launch_bounds__(1024) void k_scan(const unsigned* __restrict__ hist,
                                               unsigned* __restrict__ meta, int K) {
    __shared__ unsigned psum[1024];
    int t = threadIdx.x;
    unsigned c[4];
    unsigned local = 0;
    #pragma unroll
    for (int q = 0; q < 4; q++) { c[q] = hist[4*t + q]; local += c[q]; }
    psum[t] = local;
    __syncthreads();
    for (int o = 1; o < 1024; o <<= 1) {
        unsigned v = (t >= o) ? psum[t - o] : 0u;
        __syncthreads();
        psum[t] += v;
        __syncthreads();
    }
    unsigned incl = psum[t];
    unsigned excl = incl - local;
    if (excl < (unsigned)K && (unsigned)K <= incl) {
        unsigned cum = excl;
        int B = 4*t;
        #pragma unroll
        for (int q = 0; q < 4; q++) {
            cum += c[q];
            if (cum >= (unsigned)K) { B = 4*t + q; break; }
        }
        meta[1] = (B >= NBIN - 1) ? 0xFFFFFFFFu : ((unsigned)(B + 1) << 20);
    }
}

__global__ __launch_bounds__(256) void k_compact(
        const float4* __restrict__ cos4, unsigned* __restrict__ meta,
        float* __restrict__ cval, int* __restrict__ cidx, int n4, int N) {
    unsigned keyHi = meta[1];
    int g = blockIdx.x * blockDim.x + threadIdx.x;
    if (g >= n4) return;
    float4 v = cos4[g];
    float vv[4] = {v.x, v.y, v.z, v.w};
    #pragma unroll
    for (int q = 0; q < 4; q++) {
        int i = g*4 + q;
        if (i < N) {
            unsigned u = __float_as_uint(vv[q]);
            unsigned key = (u & 0x80000000u) ? ~u : (u | 0x80000000u);
            if (key < keyHi) {
                unsigned pos = atomicAdd(&meta[0], 1u);
                if (pos < CAPC) { cval[pos] = vv[q]; cidx[pos] = i; }
            }
        }
    }
}

// Single block: exact 128-selection via 8-round MSB radix select over
// (monotone float key, idx), pairwise rank -> MLP -> softmax -> output.
__global__ __launch_bounds__(512) void k_final(
        const float* __restrict__ cval, const int* __restrict__ cidx,
        const unsigned* __restrict__ meta, const float* __restrict__ acs,
        const float* __restrict__ w_in, const float* __restrict__ b_in,
        const float* __restrict__ w2, const float* __restrict__ b2,
        const float* __restrict__ w3, const float* __restrict__ b3,
        const float* __restrict__ w_out, const float* __restrict__ b_out,
        float* __restrict__ out) {
    __shared__ unsigned kv[CAPC];
    __shared__ int      idv[CAPC];
    __shared__ unsigned char act[CAPC];
    __shared__ unsigned hist2[256];
    __shared__ unsigned remArr[9];
    __shared__ unsigned pivB[8];
    __shared__ unsigned selB_sh;
    __shared__ unsigned scnt;
    __shared__ unsigned skey[KSEL];
    __shared__ int      sidx[KSEL];
    __shared__ float    sval[KSEL];
    __shared__ float d[KSEL];
    __shared__ int   id2[KSEL];
    __shared__ float h1[HDIM], h2[HDIM], h3[HDIM], lg[KSEL];
    __shared__ float smax_sh, rsum_sh;

    const int t = threadIdx.x;
    int M = (int)meta[0];
    if (M > CAPC) M = CAPC;

    for (int i = t; i < M; i += 512) {
        float v = cval[i];
        unsigned u = __float_as_uint(v);
        kv[i]  = (u & 0x80000000u) ? ~u : (u | 0x80000000u);
        idv[i] = cidx[i];
        act[i] = 1;
    }
    if (t == 0) remArr[0] = KSEL - 1;   // 0-indexed rank of the pivot
    if (t < KSEL) {
        skey[t] = 0xFFFFFFFFu; sidx[t] = 0x7FFFFFFF; sval[t] = 0.f;
        d[t] = 0.f; id2[t] = 0;
    }
    __syncthreads();

    for (int r = 0; r < 8; r++) {
        if (t < 256) hist2[t] = 0u;
        __syncthreads();
        for (int i = t; i < M; i += 512) {
            if (act[i]) {
                unsigned b = (r < 4) ? ((kv[i] >> ((3-r)*8)) & 0xFFu)
                                     : (((unsigned)idv[i] >> ((7-r)*8)) & 0xFFu);
                atomicAdd(&hist2[b], 1u);
            }
        }
        __syncthreads();
        if (t < 64) {
            unsigned s0 = hist2[4*t], s1 = hist2[4*t+1],
                     s2 = hist2[4*t+2], s3 = hist2[4*t+3];
            unsigned tot = s0 + s1 + s2 + s3;
            unsigned sc = tot;
            #pragma unroll
            for (int o = 1; o < 64; o <<= 1) {
                unsigned v2 = __shfl_up(sc, o);
                if (t >= o) sc += v2;
            }
            unsigned cb = sc - tot;
            unsigned rm = remArr[r];
            unsigned ss[4] = {s0, s1, s2, s3};
            #pragma unroll
            for (int q = 0; q < 4; q++) {
                if (cb <= rm && rm < cb + ss[q]) {
                    selB_sh = 4*t + q;
                    pivB[r] = 4*t + q;
                    remArr[r+1] = rm - cb;
                }
                cb += ss[q];
            }
        }
        __syncthreads();
        unsigned sb = selB_sh;
        for (int i = t; i < M; i += 512) {
            if (act[i]) {
                unsigned b = (r < 4) ? ((kv[i] >> ((3-r)*8)) & 0xFFu)
                                     : (((unsigned)idv[i] >> ((7-r)*8)) & 0xFFu);
                if (b != sb) act[i] = 0;
            }
        }
        __syncthreads();
    }

    unsigned kvP = (pivB[0]<<24) | (pivB[1]<<16) | (pivB[2]<<8) | pivB[3];
    unsigned idP = (pivB[4]<<24) | (pivB[5]<<16) | (pivB[6]<<8) | pivB[7];
    if (t == 0) scnt = 0u;
    __syncthreads();

    // exactly 128 qualify: (key, idx) <= pivot (keys are distinct via idx)
    for (int i = t; i < M; i += 512) {
        unsigned k = kv[i];
        unsigned ui = (unsigned)idv[i];
        if (k < kvP || (k == kvP && ui <= idP)) {
            unsigned p = atomicAdd(&scnt, 1u);
            if (p < KSEL) {
                skey[p] = k;
                sidx[p] = idv[i];
                unsigned u = (k & 0x80000000u) ? (k & 0x7FFFFFFFu) : ~k;
                sval[p] = __uint_as_float(u);
            }
        }
    }
    __syncthreads();

    // pairwise rank -> sorted ascending by (val, idx), matching lax.top_k
    if (t < KSEL) {
        unsigned mk = skey[t], mi = (unsigned)sidx[t];
        int rank = 0;
        for (int j = 0; j < KSEL; j++) {
            unsigned jk = skey[j], ji = (unsigned)sidx[j];
            rank += (jk < mk || (jk == mk && ji < mi)) ? 1 : 0;
        }
        d[rank] = sval[t];
        id2[rank] = sidx[t];
    }
    __syncthreads();

    // MLP: [128] -> [212] -> [212] -> [212] -> [128]
    if (t < HDIM) {
        float s = b_in[t];
        const float* wr = &w_in[t * KSEL];
        for (int j = 0; j < KSEL; j++) s += wr[j] * d[j];
        h1[t] = s > 0.f ? s : 0.f;
    }
    __syncthreads();
    if (t < HDIM) {
        float s = b2[t];
        const float* wr = &w2[t * HDIM];
        for (int j = 0; j < HDIM; j++) s += wr[j] * h1[j];
        h2[t] = s > 0.f ? s : 0.f;
    }
    __syncthreads();
    if (t < HDIM) {
        float s = b3[t];
        const float* wr = &w3[t * HDIM];
        for (int j = 0; j < HDIM; j++) s += wr[j] * h2[j];
        h3[t] = s > 0.f ? s : 0.f;
    }
    __syncthreads();
    if (t < KSEL) {
        float s = b_out[t];
        const float* wr = &w_out[t * HDIM];
        for (int j = 0; j < HDIM; j++) s += wr[j] * h3[j];
        lg[t] = s;
    }
    __syncthreads();

    // parallel softmax over 128 logits
    if (t < 64) {
        float a = fmaxf(lg[t], lg[t + 64]);
        #pragma unroll
        for (int o = 32; o >= 1; o >>= 1) a = fmaxf(a, __shfl_xor(a, o));
        if (t == 0) smax_sh = a;
    }
    __syncthreads();
    if (t < KSEL) lg[t] = __expf(lg[t] - smax_sh);
    __syncthreads();
    if (t < 64) {
        float s = lg[t] + lg[t + 64];
        #pragma unroll
        for (int o = 32; o >= 1; o >>= 1) s += __shfl_xor(s, o);
        if (t == 0) rsum_sh = 1.0f / s;
    }
    __syncthreads();

    if (t < DAC) {
        float s = 0.f;
        for (int j = 0; j < KSEL; j++)
            s += lg[j] * acs[(size_t)id2[j] * DAC + t];
        out[t] = s * rsum_sh;
    }
}

extern "C" void kernel_launch(void* const* d_in, const int* in_sizes, int n_in,
                              void* d_out, int out_size, void* d_ws, size_t ws_size,
                              hipStream_t stream) {
    const float* obs   = (const float*)d_in[0];
    const float* acs   = (const float*)d_in[1];
    const float* x     = (const float*)d_in[2];
    const float* w_in  = (const float*)d_in[3];
    const float* b_in  = (const float*)d_in[4];
    const float* w2    = (const float*)d_in[5];
    const float* b2    = (const float*)d_in[6];
    const float* w3    = (const float*)d_in[7];
    const float* b3    = (const float*)d_in[8];
    const float* w_out = (const float*)d_in[9];
    const float* b_out = (const float*)d_in[10];
    float* out = (float*)d_out;

    int N = in_sizes[0] / 32;

    char* ws = (char*)d_ws;
    float*    xn   = (float*)ws;                       // 32 floats
    float*    cosb = (float*)(ws + 256);               // N floats
    size_t histOff = 256 + (((size_t)N * 4 + 255) / 256) * 256;
    unsigned* hist = (unsigned*)(ws + histOff);        // 4096 u32
    unsigned* meta = (unsigned*)(ws + histOff + NBIN * 4);  // 8 u32
    float*    cval = (float*)(ws + histOff + NBIN * 4 + 256);
    int*      cidx = (int*)(ws + histOff + NBIN * 4 + 256 + CAPC * 4);

    k_init<<<1, 256, 0, stream>>>(x, xn, hist, meta);

    k_cos_hist<<<GRID1, 256, 0, stream>>>((const float4*)obs, xn, cosb, hist, N);

    k_scan<<<1, 1024, 0, stream>>>(hist, meta, KSEL);

    int n4 = (N + 3) / 4;
    k_compact<<<(n4 + 255) / 256, 256, 0, stream>>>((const float4*)cosb, meta,
                                                    cval, cidx, n4, N);

    k_final<<<1, 512, 0, stream>>>(cval, cidx, meta, acs, w_in, b_in,
                                   w2, b2, w3, b3, w_out, b_out, out);
}